// Round 7
// baseline (204.324 us; speedup 1.0000x reference)
//
#include <hip/hip_runtime.h>

// SpatioConvLayer: B=16, C_IN=C_OUT=64, T=12, N=1024, KS=3
#define NB   16
#define NC   64
#define NT   12
#define NN   1024
#define NKS  3

typedef float  f32x4  __attribute__((ext_vector_type(4)));
typedef short  s16x8  __attribute__((ext_vector_type(8)));
typedef unsigned short u16x4 __attribute__((ext_vector_type(4)));
typedef unsigned short u16x8 __attribute__((ext_vector_type(8)));
typedef unsigned short ush;

__device__ __forceinline__ ush f2bf(float f) {
    union { float f; unsigned u; } v; v.f = f;
    unsigned r = v.u + 0x7FFFu + ((v.u >> 16) & 1u);   // RNE
    return (ush)(r >> 16);
}
__device__ __forceinline__ float bf2f(ush h) {
    union { unsigned u; float f; } v; v.u = ((unsigned)h) << 16;
    return v.f;
}

// async 16-B global -> LDS (dest must be wave-uniform base + lane*16)
__device__ __forceinline__ void cp16(const void* g, void* l) {
    __builtin_amdgcn_global_load_lds(
        (const __attribute__((address_space(1))) unsigned int*)g,
        (__attribute__((address_space(3))) unsigned int*)l, 16, 0, 0);
}

// Workspace layout:
//   apan @ 0        : bf16 A-panels [g4=48][nb=32][slot=1024] x 16B (25,165,824 B)
//                     slot = row*4 + p ; row = bl*64+c (bl = bt-4*g4) ; p = d ^ (row&3)
//   kb   @ 25165824 : bf16 B-panels [mt=16][nb=32][slot=768] x 16B  (6,291,456 B)
//                     slot = j*4 + p ; j = k*64+mm ; p = d ^ (j&3)
//   thbf @ 31457280 : bf16 theta^T [o=64][ck=192]                   (24,576 B)
#define APAN_OFF 0
#define KB_OFF   25165824
#define TH_OFF   31457280

// ---------------- prep: convert + transpose + swizzle once ----------------
// Block map: [0,1536) B-panels (write-centric), [1536,1584) theta, [1584,4656) A-panels.
__global__ __launch_bounds__(256)
void spatio_prep(const float* __restrict__ x, const float* __restrict__ kern,
                 const float* __restrict__ theta,
                 ush* __restrict__ apan, ush* __restrict__ kb, ush* __restrict__ thbf)
{
    const int blk = blockIdx.x;
    const int tid = threadIdx.x;

    if (blk < 1536) {
        // ---- B panels: thread = output 16-B chunk (writes perfectly linear) ----
        int ch   = blk * 256 + tid;            // (mt*32+nb)*768 + j*4 + p
        int p    = ch & 3;
        int j    = (ch >> 2) % 192;
        int rest = (ch >> 2) / 192;            // mt*32 + nb
        int nb   = rest & 31, mt = rest >> 5;
        int d    = p ^ (j & 3);
        int k    = j >> 6, mm = j & 63;
        int col  = (k << 10) + (mt << 6) + mm;
        u16x8 w;
#pragma unroll
        for (int i = 0; i < 8; ++i) {
            int n = nb * 32 + d * 8 + i;
            w[i] = f2bf(kern[(size_t)n * (NKS * NN) + col]);
        }
        ((u16x8*)kb)[ch] = w;
    } else if (blk < 1584) {
        // ---- theta^T: thbf[o][k*64+c] ----
        int id = (blk - 1536) * 256 + tid;
        if (id < 12288) {
            int row = id >> 6, o = id & 63;   // row = c*3 + k
            int c = row / 3, k = row - 3 * c;
            thbf[o * 192 + k * 64 + c] = f2bf(theta[id]);
        }
    } else {
        // ---- A panels: two adjacent 16-B slots/thread (64-B contiguous reads) ----
        int id   = (blk - 1584) * 256 + tid;   // 0..786431
        int ch0  = id * 2;                     // even chunk index
        int slot = ch0 & 1023;
        int g4nb = ch0 >> 10;
        int nb   = g4nb & 31, g4 = g4nb >> 5;
        int row  = slot >> 2;
        int q2   = slot & 3;                   // 0 or 2
        int d0   = q2 ^ (row & 3);
        int dbase = d0 & ~1;
        int bl   = row >> 6, c = row & 63;
        int bt   = 4 * g4 + bl;
        int b    = bt / NT, t = bt - NT * b;
        const float* src = x + ((size_t)((b * NC + c) * NT + t)) * NN + nb * 32 + dbase * 8;
        float4 v0 = ((const float4*)src)[0];
        float4 v1 = ((const float4*)src)[1];
        float4 v2 = ((const float4*)src)[2];
        float4 v3 = ((const float4*)src)[3];
        u16x8 lo, hi;
        lo[0]=f2bf(v0.x); lo[1]=f2bf(v0.y); lo[2]=f2bf(v0.z); lo[3]=f2bf(v0.w);
        lo[4]=f2bf(v1.x); lo[5]=f2bf(v1.y); lo[6]=f2bf(v1.z); lo[7]=f2bf(v1.w);
        hi[0]=f2bf(v2.x); hi[1]=f2bf(v2.y); hi[2]=f2bf(v2.z); hi[3]=f2bf(v2.w);
        hi[4]=f2bf(v3.x); hi[5]=f2bf(v3.y); hi[6]=f2bf(v3.z); hi[7]=f2bf(v3.w);
        ((u16x8*)apan)[ch0]     = (d0 & 1) ? hi : lo;
        ((u16x8*)apan)[ch0 + 1] = (d0 & 1) ? lo : hi;
    }
}

// ---------------- main: 256x192 tile, 512 thr, dbuf, fused stage 2 ----------------
__global__ __launch_bounds__(512, 2)
void spatio_main(const ush* __restrict__ apan, const ush* __restrict__ kb,
                 const ush* __restrict__ thbf, const float* __restrict__ bias,
                 float* __restrict__ out)
{
    // LDS: buf0 @0 (A 16K + B 12K = 28672), buf1 @28672, stash @57344 (2 x 16 KB)
    //      stage2 xm[64][200] (25.6 KB) overlays buf0 after stage 1
    __shared__ __attribute__((aligned(128))) char smem[90112];
    ush (*xm)[200] = (ush (*)[200])smem;
    ush (*stA)[32] = (ush (*)[32])(smem + 57344);   // n-cols m_base..+31
    ush (*stB)[32] = (ush (*)[32])(smem + 73728);   // n-cols m_base+32..+63

    const int tid  = threadIdx.x;
    const int g4   = blockIdx.x;          // 4-bt group 0..47
    const int mt   = blockIdx.y;          // m-tile 0..15
    const int m_base = mt * 64;
    const int lane = tid & 63;
    const int wid  = tid >> 6;            // 0..7
    const int wr   = wid >> 1;            // row quarter = bt local (0..3)
    const int wn   = wid & 1;             // col half (96 j)
    const int quad = lane >> 4;
    const int l16  = lane & 15;
    const int pofs = (quad ^ (l16 & 3)) * 8;   // swizzled 16-B chunk (u16 units)

    const char* apan_c = (const char*)apan + ((size_t)g4 << 19);        // g4*32*1024*16
    const char* kb_c   = (const char*)kb + ((size_t)mt * 393216);

    f32x4 acc[4][6];
#pragma unroll
    for (int i = 0; i < 4; ++i)
#pragma unroll
        for (int j = 0; j < 6; ++j) acc[i][j] = (f32x4){0.f, 0.f, 0.f, 0.f};

    // prologue: preload iter 0 into buf0
#pragma unroll
    for (int i = 0; i < 2; ++i)
        cp16(apan_c + (i * 512 + tid) * 16, smem + (i * 512 + tid) * 16);
    cp16(kb_c + tid * 16, smem + 16384 + tid * 16);
    if (tid < 256)
        cp16(kb_c + (512 + tid) * 16, smem + 16384 + (512 + tid) * 16);

    // ===== stage 1: xm = x @ K ; 32 iters, 1 barrier/iter, dbuf =====
    for (int it = 0; it < 32; ++it) {
        const int p = it & 1;
        char* buf = smem + p * 28672;
        __syncthreads();                   // buf[p] loads done; buf[p^1] readers done
        if (it < 31) {                     // prefetch it+1 into buf[p^1]
            const char* asrc = apan_c + ((size_t)(it + 1) << 14);
            const char* bsrc = kb_c + (size_t)(it + 1) * 12288;
            char* nbuf = smem + (p ^ 1) * 28672;
#pragma unroll
            for (int i = 0; i < 2; ++i)
                cp16(asrc + (i * 512 + tid) * 16, nbuf + (i * 512 + tid) * 16);
            cp16(bsrc + tid * 16, nbuf + 16384 + tid * 16);
            if (tid < 256)
                cp16(bsrc + (512 + tid) * 16, nbuf + 16384 + (512 + tid) * 16);
        }
        if ((it >> 1) == mt) {
            // stash de-swizzled residual tile (bf16 x rows for this m-tile)
            const char* asrc = apan_c + ((size_t)it << 14);
            char* sb = smem + 57344 + (it & 1) * 16384;
#pragma unroll
            for (int i = 0; i < 2; ++i) {
                int m = i * 512 + tid;
                int slot = (m & ~3) | ((m & 3) ^ ((m >> 2) & 3));
                cp16(asrc + slot * 16, sb + m * 16);
            }
        }

        ush (*As)[32] = (ush (*)[32])buf;
        ush (*Bs)[32] = (ush (*)[32])(buf + 16384);
        s16x8 af[4], bf[6];
#pragma unroll
        for (int rb = 0; rb < 4; ++rb)
            af[rb] = *(const s16x8*)&As[64 * wr + 16 * rb + l16][pofs];
#pragma unroll
        for (int jb = 0; jb < 6; ++jb)
            bf[jb] = *(const s16x8*)&Bs[96 * wn + 16 * jb + l16][pofs];
#pragma unroll
        for (int rb = 0; rb < 4; ++rb)
#pragma unroll
            for (int jb = 0; jb < 6; ++jb)
                acc[rb][jb] = __builtin_amdgcn_mfma_f32_16x16x32_bf16(af[rb], bf[jb], acc[rb][jb], 0, 0, 0);
    }

    // ===== stage 2: gc = th^T @ xm ; one bt per pass (4 passes) =====
    const int oh2 = wid & 3;               // o 16-block
    const int mh  = wid >> 2;              // m half (32)
    float bo[4];
#pragma unroll
    for (int r = 0; r < 4; ++r) bo[r] = bias[16 * oh2 + 4 * quad + r];

    for (int pass = 0; pass < 4; ++pass) {
        __syncthreads();               // stage-1/previous-pass LDS reads done
        if (wr == pass) {
            // 2 waves write acc -> xm[mm][k*64+c] (B-operand layout)
#pragma unroll
            for (int rb = 0; rb < 4; ++rb)
#pragma unroll
                for (int jb = 0; jb < 6; ++jb) {
                    int J  = 96 * wn + 16 * jb + l16;
                    int kk = J >> 6, mmw = J & 63;
                    int ck0 = kk * 64 + 16 * rb + 4 * quad;
                    u16x4 w;
                    w.x = f2bf(acc[rb][jb].x); w.y = f2bf(acc[rb][jb].y);
                    w.z = f2bf(acc[rb][jb].z); w.w = f2bf(acc[rb][jb].w);
                    *(u16x4*)&xm[mmw][ck0] = w;
                }
        }
        __syncthreads();

        f32x4 acc2[2];
#pragma unroll
        for (int jb = 0; jb < 2; ++jb) acc2[jb] = (f32x4){0.f, 0.f, 0.f, 0.f};
#pragma unroll
        for (int ks = 0; ks < 6; ++ks) {       // K = 192
            s16x8 a2 = *(const s16x8*)(thbf + (size_t)(16 * oh2 + l16) * 192 + ks * 32 + quad * 8);
#pragma unroll
            for (int jb = 0; jb < 2; ++jb) {
                s16x8 b2 = *(const s16x8*)&xm[16 * (2 * mh + jb) + l16][ks * 32 + quad * 8];
                acc2[jb] = __builtin_amdgcn_mfma_f32_16x16x32_bf16(a2, b2, acc2[jb], 0, 0, 0);
            }
        }

        // epilogue: out = relu(gc + bias + x_bf16) ; residual from LDS stash
        const int bt = 4 * g4 + pass;
        const int b2i = bt / NT, t2 = bt - NT * b2i;
#pragma unroll
        for (int jb = 0; jb < 2; ++jb) {
            int mm = 16 * (2 * mh + jb) + l16;
#pragma unroll
            for (int r = 0; r < 4; ++r) {
                int o = 16 * oh2 + 4 * quad + r;
                int row = pass * 64 + o;
                ush rv = mh ? stB[row][mm - 32] : stA[row][mm];
                size_t idx = (((size_t)(b2i * NC + o) * NT + t2) * NN) + m_base + mm;
                float v = acc2[jb][r] + bo[r] + bf2f(rv);
                out[idx] = fmaxf(v, 0.f);
            }
        }
    }
}

extern "C" void kernel_launch(void* const* d_in, const int* in_sizes, int n_in,
                              void* d_out, int out_size, void* d_ws, size_t ws_size,
                              hipStream_t stream) {
    const float* x     = (const float*)d_in[0];
    const float* kern  = (const float*)d_in[1];
    const float* theta = (const float*)d_in[2];
    const float* bias  = (const float*)d_in[3];
    float* out = (float*)d_out;
    (void)in_sizes; (void)n_in; (void)out_size; (void)ws_size;

    ush* apan = (ush*)((char*)d_ws + APAN_OFF);
    ush* kbp  = (ush*)((char*)d_ws + KB_OFF);
    ush* thbf = (ush*)((char*)d_ws + TH_OFF);

    hipLaunchKernelGGL(spatio_prep, dim3(4656), dim3(256), 0, stream,
                       x, kern, theta, apan, kbp, thbf);
    hipLaunchKernelGGL(spatio_main, dim3(48, 16), dim3(512), 0, stream,
                       apan, kbp, thbf, bias, out);
}